// Round 1
// baseline (125.583 us; speedup 1.0000x reference)
//
#include <hip/hip_runtime.h>
#include <math.h>

// Problem constants (from reference setup_inputs)
constexpr int kB  = 32;
constexpr int kS  = 4096;
constexpr int kH  = 1024;
constexpr int kNC = 128;          // S-chunks per batch
constexpr int kCH = kS / kNC;     // 32 rows per chunk
constexpr int WPB = 4;            // waves per block (256 threads)

// ---------------------------------------------------------------------------
// Pass 1: one wave per (batch, chunk). Flash-style online softmax over the
// chunk's 32 context rows. Each row is read ONCE and used as both K (dot with
// q) and V (weighted accumulate). Emits raw logits + per-chunk partials
// (m, l, acc[1024]).
// Lane j holds h-positions {0,1,2,3}+4*j + 256*k for k=0..3 (float4 strided).
// ---------------------------------------------------------------------------
__global__ __launch_bounds__(256, 4) void attn_pass1(
    const float* __restrict__ q,      // [B, H]
    const float* __restrict__ ctx,    // [B, S, H]
    float* __restrict__ scores,       // [B, S]   raw logits
    float* __restrict__ pm,           // [B*NC]   running max per chunk
    float* __restrict__ pl,           // [B*NC]   running denom per chunk
    float* __restrict__ pacc)         // [B*NC, H] unnormalized weighted V-sum
{
  const int lane = threadIdx.x & 63;
  const int wid  = threadIdx.x >> 6;
  const int wave = blockIdx.x * WPB + wid;   // 0 .. B*NC-1
  const int b    = wave / kNC;
  const int c    = wave % kNC;

  // q fragment in registers (same h-positions as the v loads below)
  const float4* qp = reinterpret_cast<const float4*>(q + (size_t)b * kH) + lane;
  const float4 q0 = qp[0], q1 = qp[64], q2 = qp[128], q3 = qp[192];

  const float4* cp =
      reinterpret_cast<const float4*>(ctx + ((size_t)b * kS + (size_t)c * kCH) * kH) + lane;

  float m = -3.0e38f, l = 0.0f;
  float4 a0 = make_float4(0.f, 0.f, 0.f, 0.f), a1 = a0, a2 = a0, a3 = a0;
  float myscore = 0.0f;   // lane r stashes row r's logit (r < 32)

  // prefetch row 0
  float4 v0 = cp[0], v1 = cp[64], v2 = cp[128], v3 = cp[192];

  for (int r = 0; r < kCH; ++r) {
    const float4 w0 = v0, w1 = v1, w2 = v2, w3 = v3;
    if (r + 1 < kCH) {   // prefetch next row while we compute this one
      const float4* np = cp + (size_t)(r + 1) * 256;
      v0 = np[0]; v1 = np[64]; v2 = np[128]; v3 = np[192];
    }

    // partial dot (16 elements per lane)
    float d = w0.x*q0.x + w0.y*q0.y + w0.z*q0.z + w0.w*q0.w
            + w1.x*q1.x + w1.y*q1.y + w1.z*q1.z + w1.w*q1.w
            + w2.x*q2.x + w2.y*q2.y + w2.z*q2.z + w2.w*q2.w
            + w3.x*q3.x + w3.y*q3.y + w3.z*q3.z + w3.w*q3.w;

    // wave-64 butterfly reduce -> full dot in every lane
    #pragma unroll
    for (int off = 32; off >= 1; off >>= 1) d += __shfl_xor(d, off, 64);

    if (lane == r) myscore = d;

    // online softmax update (first iter: exp(-3e38 - nm) flushes to 0)
    const float nm = fmaxf(m, d);
    const float sc = __expf(m - nm);
    const float p  = __expf(d - nm);
    m = nm;
    l = l * sc + p;
    a0.x = a0.x*sc + p*w0.x; a0.y = a0.y*sc + p*w0.y; a0.z = a0.z*sc + p*w0.z; a0.w = a0.w*sc + p*w0.w;
    a1.x = a1.x*sc + p*w1.x; a1.y = a1.y*sc + p*w1.y; a1.z = a1.z*sc + p*w1.z; a1.w = a1.w*sc + p*w1.w;
    a2.x = a2.x*sc + p*w2.x; a2.y = a2.y*sc + p*w2.y; a2.z = a2.z*sc + p*w2.z; a2.w = a2.w*sc + p*w2.w;
    a3.x = a3.x*sc + p*w3.x; a3.y = a3.y*sc + p*w3.y; a3.z = a3.z*sc + p*w3.z; a3.w = a3.w*sc + p*w3.w;
  }

  // epilogue: coalesced stores of logits + partials
  if (lane < kCH) scores[(size_t)b * kS + (size_t)c * kCH + lane] = myscore;
  if (lane == 0) { pm[wave] = m; pl[wave] = l; }
  float4* pap = reinterpret_cast<float4*>(pacc + (size_t)wave * kH) + lane;
  pap[0] = a0; pap[64] = a1; pap[128] = a2; pap[192] = a3;
}

// ---------------------------------------------------------------------------
// Pass 2: grid (B, 5). Every block recomputes global (m_g, l_g) from the 128
// chunk partials (cheap: 256 floats). Blocks y=0..3 combine acc partials for
// one 256-wide h slice and write out = tanh(acc/l). Block y=4 normalizes the
// raw logits into the attn output.
// d_out layout: [out (B*H floats)] ++ [attn (B*S floats)]
// ---------------------------------------------------------------------------
__global__ __launch_bounds__(256) void attn_pass2(
    const float* __restrict__ scores,
    const float* __restrict__ pm,
    const float* __restrict__ pl,
    const float* __restrict__ pacc,
    float* __restrict__ out)
{
  const int b  = blockIdx.x;
  const int by = blockIdx.y;
  const int t  = threadIdx.x;

  __shared__ float red[256];
  __shared__ float wgt[kNC];

  // global max over this batch's chunk maxima
  float mi = (t < kNC) ? pm[b * kNC + t] : -3.0e38f;
  red[t] = mi;
  __syncthreads();
  #pragma unroll
  for (int o = 128; o >= 1; o >>= 1) {
    if (t < o) red[t] = fmaxf(red[t], red[t + o]);
    __syncthreads();
  }
  const float m_g = red[0];
  __syncthreads();

  // global denom + per-chunk rescale weights
  float li = 0.0f;
  if (t < kNC) {
    const float wi = __expf(mi - m_g);
    wgt[t] = wi;
    li = pl[b * kNC + t] * wi;
  }
  red[t] = li;
  __syncthreads();
  #pragma unroll
  for (int o = 128; o >= 1; o >>= 1) {
    if (t < o) red[t] += red[t + o];
    __syncthreads();
  }
  const float inv = 1.0f / red[0];

  if (by < 4) {
    // combine acc partials for h = by*256 + t
    const int h = by * 256 + t;
    const float* pa = pacc + (size_t)b * kNC * kH + h;
    float acc = 0.0f;
    #pragma unroll 4
    for (int i = 0; i < kNC; ++i) acc += wgt[i] * pa[(size_t)i * kH];
    out[(size_t)b * kH + h] = tanhf(acc * inv);
  } else {
    // normalize logits -> attn
    float* ab = out + (size_t)kB * kH + (size_t)b * kS;
    const float* sb = scores + (size_t)b * kS;
    for (int s = t; s < kS; s += 256)
      ab[s] = __expf(sb[s] - m_g) * inv;
  }
}

extern "C" void kernel_launch(void* const* d_in, const int* in_sizes, int n_in,
                              void* d_out, int out_size, void* d_ws, size_t ws_size,
                              hipStream_t stream) {
  const float* q   = (const float*)d_in[0];   // output: (B,1,H) fp32 — the query
  const float* ctx = (const float*)d_in[1];   // context: (B,S,H) fp32
  float* out = (float*)d_out;
  float* ws  = (float*)d_ws;

  // workspace layout (floats): scores[B*S] | pm[B*NC] | pl[B*NC] | pacc[B*NC*H]
  float* scores = ws;
  float* pm     = scores + (size_t)kB * kS;
  float* pl     = pm + kB * kNC;
  float* pacc   = pl + kB * kNC;   // offset 139264 floats -> 16B aligned

  attn_pass1<<<dim3(kB * kNC / WPB), 256, 0, stream>>>(q, ctx, scores, pm, pl, pacc);
  attn_pass2<<<dim3(kB, 5), 256, 0, stream>>>(scores, pm, pl, pacc, out);
}